// Round 2
// 480.848 us; speedup vs baseline: 1.0864x; 1.0864x over previous
//
#include <hip/hip_runtime.h>
#include <hip/hip_bf16.h>
#include <cstdint>
#include <cstddef>

#define LRELU_ALPHA 0.2f
#define LOG2E 1.44269504088896f

typedef __attribute__((ext_vector_type(8))) short short8;
typedef __attribute__((ext_vector_type(4))) float f32x4;
typedef _Float16 h2v __attribute__((ext_vector_type(2)));

__device__ __forceinline__ unsigned short f2bf(float f) {
    unsigned int u = __float_as_uint(f);
    unsigned int r = (u + 0x7fffu + ((u >> 16) & 1u)) >> 16;   // RTN-even
    return (unsigned short)r;
}
__device__ __forceinline__ float bf2f(unsigned int lo16) {
    return __uint_as_float(lo16 << 16);
}
__device__ __forceinline__ unsigned int pk2(float a, float b) {
    return (unsigned int)f2bf(a) | ((unsigned int)f2bf(b) << 16);
}
__device__ __forceinline__ float fexp2(float x) {
#if __has_builtin(__builtin_amdgcn_exp2f)
    return __builtin_amdgcn_exp2f(x);
#else
    return __expf(x * 0.69314718056f);
#endif
}
__device__ __forceinline__ h2v pkrtz(float a, float b) {
#if __has_builtin(__builtin_amdgcn_cvt_pkrtz)
    auto r = __builtin_amdgcn_cvt_pkrtz(a, b);   // __fp16 ext_vector(2) on this clang
    union { decltype(r) i; h2v o; } u;
    u.i = r;
    return u.o;
#else
    h2v r; r.x = (_Float16)a; r.y = (_Float16)b; return r;
#endif
}
// pack_lo(a,b) = {lo16: a.lo16, hi16: b.lo16}; pack_hi = same for hi halves
__device__ __forceinline__ unsigned int pack_lo(unsigned int a, unsigned int b) {
#if __has_builtin(__builtin_amdgcn_perm)
    return __builtin_amdgcn_perm(a, b, 0x01000504u);
#else
    return (a & 0xffffu) | (b << 16);
#endif
}
__device__ __forceinline__ unsigned int pack_hi(unsigned int a, unsigned int b) {
#if __has_builtin(__builtin_amdgcn_perm)
    return __builtin_amdgcn_perm(a, b, 0x03020706u);
#else
    return (a >> 16) | (b & 0xffff0000u);
#endif
}
union U32H2 { unsigned int u; h2v h; };
__device__ __forceinline__ float dot2f(unsigned int a, h2v w, float acc) {
    U32H2 c; c.u = a;
#if __has_builtin(__builtin_amdgcn_fdot2)
    return __builtin_amdgcn_fdot2(c.h, w, acc, false);
#else
    return acc + (float)c.h.x * (float)w.x + (float)c.h.y * (float)w.y;
#endif
}

// ---------------- CSR build (padded to multiple of 8 per row) ----------------

__global__ void hist_k(const int* __restrict__ ei, int* __restrict__ counts,
                       int* __restrict__ rank, int E_) {
    int e = blockIdx.x * 256 + threadIdx.x;
    if (e < E_) {
        int r = ei[e];
        rank[e] = atomicAdd(&counts[r], 1);
    }
}

// fill scol with dummy node N; set dummy sdst slots; zero dummy hW rows
__global__ void fill_pad_k(int* __restrict__ scol, float* __restrict__ sdA,
                           float* __restrict__ sdB, float* __restrict__ sdC,
                           unsigned int* __restrict__ hW, int N_, int total) {
    int i = blockIdx.x * 256 + threadIdx.x;
    if (i < total) scol[i] = N_;
    if (blockIdx.x == 0) {
        int t = threadIdx.x;
        if (t < 4) { sdA[N_ * 4 + t] = -1e30f; sdB[N_ * 4 + t] = -1e30f; }
        if (t == 4) sdC[N_] = -1e30f;
        if (t >= 32 && t < 64)  hW[(size_t)N_ * 32 + (t - 32)] = 0u;   // DHT=64 dummy row
        if (t >= 64 && t < 128) hW[(size_t)N_ * 64 + (t - 64)] = 0u;   // DHT=128 dummy row
    }
}

__global__ void scan_block_k(const int* __restrict__ counts, int* __restrict__ tmp,
                             int* __restrict__ bsum, int n) {
    __shared__ int s[256];
    int i = blockIdx.x * 256 + threadIdx.x;
    int v = (i < n) ? ((counts[i] + 7) & ~7) : 0;   // round rows up to x8
    s[threadIdx.x] = v;
    __syncthreads();
    for (int d = 1; d < 256; d <<= 1) {
        int t_ = (threadIdx.x >= d) ? s[threadIdx.x - d] : 0;
        __syncthreads();
        s[threadIdx.x] += t_;
        __syncthreads();
    }
    if (i < n) tmp[i] = s[threadIdx.x];
    if (threadIdx.x == 255) bsum[blockIdx.x] = s[255];
}

__global__ void scan_sums_k(int* bsum, int nb) {
    __shared__ int s[512];
    int v = ((int)threadIdx.x < nb) ? bsum[threadIdx.x] : 0;
    s[threadIdx.x] = v;
    __syncthreads();
    for (int d = 1; d < 512; d <<= 1) {
        int t_ = ((int)threadIdx.x >= d) ? s[threadIdx.x - d] : 0;
        __syncthreads();
        s[threadIdx.x] += t_;
        __syncthreads();
    }
    if ((int)threadIdx.x < nb) bsum[threadIdx.x] = s[threadIdx.x] - v;  // exclusive
}

__global__ void finalize_k(const int* __restrict__ tmp, const int* __restrict__ bsum,
                           int* __restrict__ off, int n) {
    int i = blockIdx.x * 256 + threadIdx.x;
    if (i < n) off[i + 1] = tmp[i] + bsum[blockIdx.x];
    if (i == 0) off[0] = 0;
}

__global__ void scatter_k(const int* __restrict__ ei, const int* __restrict__ rank,
                          const int* __restrict__ off, int* __restrict__ scol, int E_) {
    int e = blockIdx.x * 256 + threadIdx.x;
    if (e < E_) {
        int r = ei[e];
        int pos = off[r] + rank[e];
        scol[pos] = ei[E_ + e];
    }
}

// ---------------- single-launch weight repack: all 4 matrices -> WT[n][k] bf16 ----------

__global__ void repack_all(const float* __restrict__ Win, const float* __restrict__ Whid,
                           const float* __restrict__ Wout,
                           unsigned short* __restrict__ W0, unsigned short* __restrict__ W1,
                           unsigned short* __restrict__ W2, unsigned short* __restrict__ W3) {
    int i = blockIdx.x * 256 + threadIdx.x;
    if (i < 16384) {                       // Win [128][128], HD=1
        int n = i >> 7, k = i & 127;
        W0[i] = f2bf(Win[k * 128 + n]);
    } else if (i < 49152) {                // Whid [2][4][128][32], HD=4
        int j = i - 16384;
        int l = j >> 14;
        int jj = j & 16383;
        int n = jj >> 7, k = jj & 127;
        int hd = n >> 5, c = n & 31;
        float v = Whid[(size_t)l * 16384 + (hd * 128 + k) * 32 + c];
        (l ? W2 : W1)[jj] = f2bf(v);
    } else if (i < 57344) {                // Wout [128][64], HD=1
        int j = i - 49152;
        int n = j >> 7, k = j & 127;
        W3[j] = f2bf(Wout[k * 64 + n]);
    }
}

// ---------------- MFMA GEMM: Y[n, 0:KJ] = act(X[n,0:128] @ W[128,KJ] + bias) -------------
// OUTM: 0=f32, 1=bf16, 2=f16. A: fp32 (converted) or packed bf16 (ABF16).
// C/D layout: col=lane&15, row=(lane>>4)*4+reg.

template <int KJ, bool ELU_ACT, bool BIAS, int OUTM, bool ABF16>
__global__ __launch_bounds__(256) void gemm_mfma(const void* __restrict__ Xv,
                                                 const unsigned short* __restrict__ WT,
                                                 const float* __restrict__ bias,
                                                 void* __restrict__ Yv, int nRows) {
    constexpr int NT = KJ / 16;
    constexpr int WS = 136;
    __shared__ unsigned short sWT[KJ * WS];
    int t = threadIdx.x;
    for (int i = t; i < KJ * 16; i += 256) {
        int n = i >> 4, k8 = i & 15;
        uint4 v = *(const uint4*)&WT[n * 128 + k8 * 8];
        *(uint4*)&sWT[n * WS + k8 * 8] = v;
    }
    __syncthreads();

    int lane = t & 63;
    int wv = t >> 6;
    int m0 = blockIdx.x * 128 + wv * 32;
    int l16 = lane & 15;
    int q4 = lane >> 4;

    short8 afr[4][2];
    #pragma unroll
    for (int rt = 0; rt < 2; rt++) {
        int row = m0 + rt * 16 + l16;
        bool vr = row < nRows;
        if (ABF16) {
            const unsigned int* xp = (const unsigned int*)Xv + (size_t)row * 64 + q4 * 4;
            #pragma unroll
            for (int kk = 0; kk < 4; kk++) {
                uint4 u = make_uint4(0u, 0u, 0u, 0u);
                if (vr) u = *(const uint4*)(xp + kk * 16);
                afr[kk][rt] = *(short8*)&u;
            }
        } else {
            const float* xp = (const float*)Xv + (size_t)row * 128 + q4 * 8;
            #pragma unroll
            for (int kk = 0; kk < 4; kk++) {
                float4 a0 = make_float4(0.f, 0.f, 0.f, 0.f), a1 = a0;
                if (vr) {
                    a0 = *(const float4*)(xp + kk * 32);
                    a1 = *(const float4*)(xp + kk * 32 + 4);
                }
                unsigned int u[4];
                u[0] = pk2(a0.x, a0.y); u[1] = pk2(a0.z, a0.w);
                u[2] = pk2(a1.x, a1.y); u[3] = pk2(a1.z, a1.w);
                afr[kk][rt] = *(short8*)u;
            }
        }
    }

    f32x4 acc[2][NT] = {};
    #pragma unroll
    for (int kk = 0; kk < 4; kk++) {
        #pragma unroll
        for (int ct = 0; ct < NT; ct++) {
            int n = ct * 16 + l16;
            short8 bf = *(const short8*)&sWT[n * WS + kk * 32 + q4 * 8];
            #pragma unroll
            for (int rt = 0; rt < 2; rt++)
                acc[rt][ct] = __builtin_amdgcn_mfma_f32_16x16x32_bf16(afr[kk][rt], bf, acc[rt][ct], 0, 0, 0);
        }
    }

    #pragma unroll
    for (int rt = 0; rt < 2; rt++) {
        #pragma unroll
        for (int q = 0; q < 4; q++) {
            int row = m0 + rt * 16 + q4 * 4 + q;
            if (row >= nRows) continue;
            #pragma unroll
            for (int ct = 0; ct < NT; ct++) {
                int colc = ct * 16 + l16;
                float v = acc[rt][ct][q];
                if (BIAS) v += bias[colc];
                if (ELU_ACT) v = v > 0.f ? v : (__expf(v) - 1.f);
                if (OUTM == 1) {
                    ((unsigned short*)Yv)[(size_t)row * KJ + colc] = f2bf(v);
                } else if (OUTM == 2) {
                    union { _Float16 hf; unsigned short us; } cv;
                    cv.hf = (_Float16)v;
                    ((unsigned short*)Yv)[(size_t)row * KJ + colc] = cv.us;
                } else {
                    ((float*)Yv)[(size_t)row * KJ + colc] = v;
                }
            }
        }
    }
}

// ---------------- layer-0 attention scores (reads bf16 h0), 4 nodes per wave ------------
// scores pre-scaled by log2e so downstream uses exp2 directly.

template <int H>
__global__ __launch_bounds__(256) void attn_scores16(const unsigned int* __restrict__ h2,
                                                     const float* __restrict__ a,
                                                     float* __restrict__ s_src,
                                                     float* __restrict__ s_dst, int n) {
    __shared__ float sa[H * 2 * 128];
    for (int i = threadIdx.x; i < H * 2 * 128; i += 256) sa[i] = a[i] * LOG2E;
    __syncthreads();
    int lane = threadIdx.x & 63, wv = threadIdx.x >> 6;
    int sub = lane & 15, g = lane >> 4;
    int node = (blockIdx.x * 4 + wv) * 4 + g;
    bool valid = node < n;
    int nd = valid ? node : 0;
    uint4 hv = *(const uint4*)&h2[(size_t)nd * 64 + sub * 4];
    float f[8];
    f[0] = bf2f(hv.x & 0xffffu); f[1] = bf2f(hv.x >> 16);
    f[2] = bf2f(hv.y & 0xffffu); f[3] = bf2f(hv.y >> 16);
    f[4] = bf2f(hv.z & 0xffffu); f[5] = bf2f(hv.z >> 16);
    f[6] = bf2f(hv.w & 0xffffu); f[7] = bf2f(hv.w >> 16);
    #pragma unroll
    for (int c = 0; c < 2 * H; c++) {
        const float* ap = &sa[c * 128 + sub * 8];
        float p = 0.f;
        #pragma unroll
        for (int q = 0; q < 8; q++) p += f[q] * ap[q];
        #pragma unroll
        for (int s = 1; s < 16; s <<= 1) p += __shfl_xor(p, s);
        if (sub == 0 && valid) {
            float* dst = (c & 1) ? s_dst : s_src;
            dst[node * H + (c >> 1)] = p;
        }
    }
}

// ---------------- edge pass: fp16 hW + v_dot2 aggregation + fused next-layer scores -----
// One wave per dst row; 16 lanes per row-slice, 4 edge-pair slots (g=lane>>4), each slot
// handles adjacent edges i+2g, i+2g+1 (single dwordx2 scol load). CSR rows padded to x8
// with dummy node (sdst=-1e30 -> w=0, hW row zeroed) so the loop has no validity logic.

template <int DHT, int H, bool ELU_ACT, int HN, bool BF16O>
__global__ __launch_bounds__(256) void edge_agg_v(const unsigned int* __restrict__ hW2,
                                                  const float* __restrict__ ssrc,
                                                  const float* __restrict__ sdst,
                                                  const int* __restrict__ off,
                                                  const int* __restrict__ scol,
                                                  void* __restrict__ outv,
                                                  const float* __restrict__ a_next,
                                                  float* __restrict__ ssrc_n,
                                                  float* __restrict__ sdst_n, int nRows) {
    constexpr int FPL = DHT / 16;   // features per lane
    constexpr int UPL = FPL / 2;    // packed uints per lane
    constexpr int NC = (HN > 0) ? 2 * HN : 1;
    __shared__ float sAN[NC * 128];
    if (HN > 0) {
        for (int i = threadIdx.x; i < NC * 128; i += 256) sAN[i] = a_next[i] * LOG2E;
        __syncthreads();
    }
    int lane = threadIdx.x & 63;
    int sub = lane & 15;
    int g = lane >> 4;
    int wv = threadIdx.x >> 6;
    int r = __builtin_amdgcn_readfirstlane(blockIdx.x * 4 + wv);
    if (r >= nRows) return;
    int begin = off[r], end = off[r + 1];

    int head = (H == 4) ? (sub >> 2) : 0;
    float ssl = ssrc[r * H + head];

    float acc[FPL] = {};
    float den = 0.f;

    for (int i = begin; i < end; i += 8) {
        int2 cc = *(const int2*)&scol[i + 2 * g];
        int cA = cc.x, cB = cc.y;
        float sdA = sdst[cA * H + head];
        float sdB = sdst[cB * H + head];
        unsigned int hA[UPL], hB[UPL];
        int oA = cA * (DHT / 2) + sub * UPL;
        int oB = cB * (DHT / 2) + sub * UPL;
        if (UPL == 4) {
            *(uint4*)hA = *(const uint4*)&hW2[oA];
            *(uint4*)hB = *(const uint4*)&hW2[oB];
        } else {
            *(uint2*)hA = *(const uint2*)&hW2[oA];
            *(uint2*)hB = *(const uint2*)&hW2[oB];
        }
        float lgA = ssl + sdA;
        float wA = fexp2(fmaxf(lgA, LRELU_ALPHA * lgA));
        float lgB = ssl + sdB;
        float wB = fexp2(fmaxf(lgB, LRELU_ALPHA * lgB));
        den += wA + wB;
        h2v w2 = pkrtz(wA, wB);
        #pragma unroll
        for (int q = 0; q < UPL; q++) {
            acc[2 * q]     = dot2f(pack_lo(hA[q], hB[q]), w2, acc[2 * q]);
            acc[2 * q + 1] = dot2f(pack_hi(hA[q], hB[q]), w2, acc[2 * q + 1]);
        }
    }

    #pragma unroll
    for (int s = 16; s < 64; s <<= 1) {
        den += __shfl_xor(den, s);
        #pragma unroll
        for (int p = 0; p < FPL; p++) acc[p] += __shfl_xor(acc[p], s);
    }
    float inv = den > 0.f ? 1.f / den : 0.f;

    float v[FPL];
    #pragma unroll
    for (int p = 0; p < FPL; p++) {
        float tv = acc[p] * inv;
        if (ELU_ACT) tv = tv > 0.f ? tv : (__expf(tv) - 1.f);
        v[p] = tv;
    }

    if (DHT == 128) {
        if (BF16O)
            ((unsigned int*)outv)[(size_t)r * 64 + sub * 4 + g] = pk2(v[2 * g], v[2 * g + 1]);
        else
            *(float2*)&((float*)outv)[(size_t)r * 128 + sub * 8 + 2 * g] =
                make_float2(v[2 * g], v[2 * g + 1]);
    } else {
        ((float*)outv)[(size_t)r * DHT + sub * FPL + g] = v[g];
    }

    if (HN > 0) {
        constexpr int CPG = (HN == 4) ? 2 : 1;
        #pragma unroll
        for (int cc = 0; cc < CPG; cc++) {
            int c = (HN == 4) ? (g * 2 + cc) : (g & 1);
            const float* ap = &sAN[c * 128 + sub * FPL];
            float partial = 0.f;
            #pragma unroll
            for (int p = 0; p < FPL; p++) partial += v[p] * ap[p];
            #pragma unroll
            for (int s = 1; s < 16; s <<= 1) partial += __shfl_xor(partial, s);
            if (sub == 0 && (HN == 4 || g < 2)) {
                int hd = c >> 1;
                float* dst = (c & 1) ? sdst_n : ssrc_n;
                dst[r * HN + hd] = partial;
            }
        }
    }
}

// ---------------- launcher ----------------

extern "C" void kernel_launch(void* const* d_in, const int* in_sizes, int n_in,
                              void* d_out, int out_size, void* d_ws, size_t ws_size,
                              hipStream_t stream) {
    const float* x    = (const float*)d_in[0];
    const int*   ei   = (const int*)d_in[1];
    const float* Win  = (const float*)d_in[2];
    const float* bin  = (const float*)d_in[3];
    const float* ahid = (const float*)d_in[4];
    const float* Whid = (const float*)d_in[5];
    const float* aout = (const float*)d_in[6];
    const float* Wout = (const float*)d_in[7];
    float* out = (float*)d_out;

    const int N_ = in_sizes[0] / 128;
    const int E_ = in_sizes[1] / 2;

    char* p = (char*)d_ws;
    auto alloc = [&](size_t bytes) {
        char* q = p;
        p += (bytes + 511) & ~(size_t)511;
        return q;
    };
    int* counts = (int*)alloc((size_t)N_ * 4);
    int* tmp    = (int*)alloc((size_t)N_ * 4);
    int* rank   = (int*)alloc((size_t)E_ * 4);
    int* off    = (int*)alloc((size_t)(N_ + 1) * 4);
    int* bsum   = (int*)alloc(4096);
    int* scol   = (int*)alloc((size_t)(E_ + 8 * N_ + 64) * 4);   // padded CSR
    float* ssrcA = (float*)alloc((size_t)(N_ + 1) * 4 * 4);
    float* sdstA = (float*)alloc((size_t)(N_ + 1) * 4 * 4);
    float* ssrcB = (float*)alloc((size_t)(N_ + 1) * 4 * 4);
    float* sdstB = (float*)alloc((size_t)(N_ + 1) * 4 * 4);
    float* ssrcC = (float*)alloc((size_t)(N_ + 1) * 4);
    float* sdstC = (float*)alloc((size_t)(N_ + 1) * 4);
    unsigned int* hb  = (unsigned int*)alloc((size_t)N_ * 64 * 4);        // h  bf16 packed
    unsigned int* hWb = (unsigned int*)alloc((size_t)(N_ + 1) * 64 * 4);  // hW fp16 packed (+dummy row)
    unsigned short* WT0 = (unsigned short*)alloc(128 * 128 * 2);
    unsigned short* WT1 = (unsigned short*)alloc(128 * 128 * 2);
    unsigned short* WT2 = (unsigned short*)alloc(128 * 128 * 2);
    unsigned short* WT3 = (unsigned short*)alloc(64 * 128 * 2);

    int NB = (N_ + 255) / 256;
    int EB = (E_ + 255) / 256;
    int RT = (N_ + 127) / 128;
    int NW = (N_ + 3) / 4;
    int PADTOT = E_ + 8 * N_;

    // CSR by destination (= edge_index[0], the softmax segment key), rows padded to x8
    (void)hipMemsetAsync(counts, 0, (size_t)N_ * 4, stream);
    hist_k<<<EB, 256, 0, stream>>>(ei, counts, rank, E_);
    fill_pad_k<<<(PADTOT + 255) / 256, 256, 0, stream>>>(scol, sdstA, sdstB, sdstC, hWb, N_, PADTOT);
    scan_block_k<<<NB, 256, 0, stream>>>(counts, tmp, bsum, N_);
    scan_sums_k<<<1, 512, 0, stream>>>(bsum, NB);
    finalize_k<<<NB, 256, 0, stream>>>(tmp, bsum, off, N_);
    scatter_k<<<EB, 256, 0, stream>>>(ei, rank, off, scol, E_);

    // all weight repacks in one launch
    repack_all<<<224, 256, 0, stream>>>(Win, Whid, Wout, WT0, WT1, WT2, WT3);

    // input linear + ELU -> h0 bf16
    gemm_mfma<128, true, true, 1, false><<<RT, 256, 0, stream>>>(x, WT0, bin, hb, N_);

    // layer-0 attention scores (reads bf16 h0), log2e-scaled
    attn_scores16<4><<<(N_ + 15) / 16, 256, 0, stream>>>(hb, ahid, ssrcA, sdstA, N_);

    // hidden layer 1: hW0 = h0 @ Wcat0 (fp16) ; aggregate -> h1 bf16 (+ scores for a_hid[1])
    gemm_mfma<128, false, false, 2, true><<<RT, 256, 0, stream>>>(hb, WT1, nullptr, hWb, N_);
    edge_agg_v<128, 4, true, 4, true><<<NW, 256, 0, stream>>>(
        hWb, ssrcA, sdstA, off, scol, hb, ahid + 4 * 2 * 128, ssrcB, sdstB, N_);

    // hidden layer 2: hW1 = h1 @ Wcat1 (fp16) ; aggregate -> h2 bf16 (+ scores for a_out)
    gemm_mfma<128, false, false, 2, true><<<RT, 256, 0, stream>>>(hb, WT2, nullptr, hWb, N_);
    edge_agg_v<128, 4, true, 1, true><<<NW, 256, 0, stream>>>(
        hWb, ssrcB, sdstB, off, scol, hb, aout, ssrcC, sdstC, N_);

    // output layer: hW2 = h2 @ Wout (fp16) ; aggregate -> out fp32
    gemm_mfma<64, false, false, 2, true><<<RT, 256, 0, stream>>>(hb, WT3, nullptr, hWb, N_);
    edge_agg_v<64, 1, false, 0, false><<<NW, 256, 0, stream>>>(
        hWb, ssrcC, sdstC, off, scol, out, nullptr, nullptr, nullptr, N_);
}

// Round 3
// 468.454 us; speedup vs baseline: 1.1152x; 1.0265x over previous
//
#include <hip/hip_runtime.h>
#include <hip/hip_bf16.h>
#include <cstdint>
#include <cstddef>

#define LRELU_ALPHA 0.2f
#define LOG2E 1.44269504088896f

typedef __attribute__((ext_vector_type(8))) short short8;
typedef __attribute__((ext_vector_type(4))) float f32x4;
typedef _Float16 h2v __attribute__((ext_vector_type(2)));

__device__ __forceinline__ unsigned short f2bf(float f) {
    unsigned int u = __float_as_uint(f);
    unsigned int r = (u + 0x7fffu + ((u >> 16) & 1u)) >> 16;   // RTN-even
    return (unsigned short)r;
}
__device__ __forceinline__ float bf2f(unsigned int lo16) {
    return __uint_as_float(lo16 << 16);
}
__device__ __forceinline__ unsigned int pk2(float a, float b) {
    return (unsigned int)f2bf(a) | ((unsigned int)f2bf(b) << 16);
}
__device__ __forceinline__ float fexp2(float x) {
#if __has_builtin(__builtin_amdgcn_exp2f)
    return __builtin_amdgcn_exp2f(x);
#else
    return __expf(x * 0.69314718056f);
#endif
}
__device__ __forceinline__ h2v pkrtz(float a, float b) {
#if __has_builtin(__builtin_amdgcn_cvt_pkrtz)
    auto r = __builtin_amdgcn_cvt_pkrtz(a, b);   // __fp16 ext_vector(2) on this clang
    union { decltype(r) i; h2v o; } u;
    u.i = r;
    return u.o;
#else
    h2v r; r.x = (_Float16)a; r.y = (_Float16)b; return r;
#endif
}
// pack_lo(a,b) = {lo16: a.lo16, hi16: b.lo16}; pack_hi = same for hi halves
__device__ __forceinline__ unsigned int pack_lo(unsigned int a, unsigned int b) {
#if __has_builtin(__builtin_amdgcn_perm)
    return __builtin_amdgcn_perm(a, b, 0x01000504u);
#else
    return (a & 0xffffu) | (b << 16);
#endif
}
__device__ __forceinline__ unsigned int pack_hi(unsigned int a, unsigned int b) {
#if __has_builtin(__builtin_amdgcn_perm)
    return __builtin_amdgcn_perm(a, b, 0x03020706u);
#else
    return (a >> 16) | (b & 0xffff0000u);
#endif
}
union U32H2 { unsigned int u; h2v h; };
__device__ __forceinline__ float dot2f(unsigned int a, h2v w, float acc) {
    U32H2 c; c.u = a;
#if __has_builtin(__builtin_amdgcn_fdot2)
    return __builtin_amdgcn_fdot2(c.h, w, acc, false);
#else
    return acc + (float)c.h.x * (float)w.x + (float)c.h.y * (float)w.y;
#endif
}

// ---------------- CSR build (padded to multiple of 8 per row) ----------------

__global__ void hist_k(const int* __restrict__ ei, int* __restrict__ counts,
                       int* __restrict__ rank, int E_) {
    int e = blockIdx.x * 256 + threadIdx.x;
    if (e < E_) {
        int r = ei[e];
        rank[e] = atomicAdd(&counts[r], 1);
    }
}

// fill scol with dummy node N; set dummy sdst slots; zero dummy hW rows
__global__ void fill_pad_k(int* __restrict__ scol, float* __restrict__ sdA,
                           float* __restrict__ sdB, float* __restrict__ sdC,
                           unsigned int* __restrict__ hW, int N_, int total) {
    int i = blockIdx.x * 256 + threadIdx.x;
    if (i < total) scol[i] = N_;
    if (blockIdx.x == 0) {
        int t = threadIdx.x;
        if (t < 4) { sdA[N_ * 4 + t] = -1e30f; sdB[N_ * 4 + t] = -1e30f; }
        if (t == 4) sdC[N_] = -1e30f;
        if (t >= 32 && t < 64)  hW[(size_t)N_ * 32 + (t - 32)] = 0u;   // DHT=64 dummy row
        if (t >= 64 && t < 128) hW[(size_t)N_ * 64 + (t - 64)] = 0u;   // DHT=128 dummy row
    }
}

__global__ void scan_block_k(const int* __restrict__ counts, int* __restrict__ tmp,
                             int* __restrict__ bsum, int n) {
    __shared__ int s[256];
    int i = blockIdx.x * 256 + threadIdx.x;
    int v = (i < n) ? ((counts[i] + 7) & ~7) : 0;   // round rows up to x8
    s[threadIdx.x] = v;
    __syncthreads();
    for (int d = 1; d < 256; d <<= 1) {
        int t_ = (threadIdx.x >= d) ? s[threadIdx.x - d] : 0;
        __syncthreads();
        s[threadIdx.x] += t_;
        __syncthreads();
    }
    if (i < n) tmp[i] = s[threadIdx.x];
    if (threadIdx.x == 255) bsum[blockIdx.x] = s[255];
}

__global__ void scan_sums_k(int* bsum, int nb) {
    __shared__ int s[512];
    int v = ((int)threadIdx.x < nb) ? bsum[threadIdx.x] : 0;
    s[threadIdx.x] = v;
    __syncthreads();
    for (int d = 1; d < 512; d <<= 1) {
        int t_ = ((int)threadIdx.x >= d) ? s[threadIdx.x - d] : 0;
        __syncthreads();
        s[threadIdx.x] += t_;
        __syncthreads();
    }
    if ((int)threadIdx.x < nb) bsum[threadIdx.x] = s[threadIdx.x] - v;  // exclusive
}

__global__ void finalize_k(const int* __restrict__ tmp, const int* __restrict__ bsum,
                           int* __restrict__ off, int n) {
    int i = blockIdx.x * 256 + threadIdx.x;
    if (i < n) off[i + 1] = tmp[i] + bsum[blockIdx.x];
    if (i == 0) off[0] = 0;
}

__global__ void scatter_k(const int* __restrict__ ei, const int* __restrict__ rank,
                          const int* __restrict__ off, int* __restrict__ scol, int E_) {
    int e = blockIdx.x * 256 + threadIdx.x;
    if (e < E_) {
        int r = ei[e];
        int pos = off[r] + rank[e];
        scol[pos] = ei[E_ + e];
    }
}

// ---------------- single-launch weight repack: all 4 matrices -> WT[n][k] bf16 ----------

__global__ void repack_all(const float* __restrict__ Win, const float* __restrict__ Whid,
                           const float* __restrict__ Wout,
                           unsigned short* __restrict__ W0, unsigned short* __restrict__ W1,
                           unsigned short* __restrict__ W2, unsigned short* __restrict__ W3) {
    int i = blockIdx.x * 256 + threadIdx.x;
    if (i < 16384) {                       // Win [128][128], HD=1
        int n = i >> 7, k = i & 127;
        W0[i] = f2bf(Win[k * 128 + n]);
    } else if (i < 49152) {                // Whid [2][4][128][32], HD=4
        int j = i - 16384;
        int l = j >> 14;
        int jj = j & 16383;
        int n = jj >> 7, k = jj & 127;
        int hd = n >> 5, c = n & 31;
        float v = Whid[(size_t)l * 16384 + (hd * 128 + k) * 32 + c];
        (l ? W2 : W1)[jj] = f2bf(v);
    } else if (i < 57344) {                // Wout [128][64], HD=1
        int j = i - 49152;
        int n = j >> 7, k = j & 127;
        W3[j] = f2bf(Wout[k * 64 + n]);
    }
}

// ---------------- MFMA GEMM: Y[n, 0:KJ] = act(X[n,0:128] @ W[128,KJ] + bias) -------------
// OUTM: 0=f32, 1=bf16, 2=f16. A: fp32 (converted) or packed bf16 (ABF16).
// C/D layout: col=lane&15, row=(lane>>4)*4+reg.

template <int KJ, bool ELU_ACT, bool BIAS, int OUTM, bool ABF16>
__global__ __launch_bounds__(256) void gemm_mfma(const void* __restrict__ Xv,
                                                 const unsigned short* __restrict__ WT,
                                                 const float* __restrict__ bias,
                                                 void* __restrict__ Yv, int nRows) {
    constexpr int NT = KJ / 16;
    constexpr int WS = 136;
    __shared__ unsigned short sWT[KJ * WS];
    int t = threadIdx.x;
    for (int i = t; i < KJ * 16; i += 256) {
        int n = i >> 4, k8 = i & 15;
        uint4 v = *(const uint4*)&WT[n * 128 + k8 * 8];
        *(uint4*)&sWT[n * WS + k8 * 8] = v;
    }
    __syncthreads();

    int lane = t & 63;
    int wv = t >> 6;
    int m0 = blockIdx.x * 128 + wv * 32;
    int l16 = lane & 15;
    int q4 = lane >> 4;

    short8 afr[4][2];
    #pragma unroll
    for (int rt = 0; rt < 2; rt++) {
        int row = m0 + rt * 16 + l16;
        bool vr = row < nRows;
        if (ABF16) {
            const unsigned int* xp = (const unsigned int*)Xv + (size_t)row * 64 + q4 * 4;
            #pragma unroll
            for (int kk = 0; kk < 4; kk++) {
                uint4 u = make_uint4(0u, 0u, 0u, 0u);
                if (vr) u = *(const uint4*)(xp + kk * 16);
                afr[kk][rt] = *(short8*)&u;
            }
        } else {
            const float* xp = (const float*)Xv + (size_t)row * 128 + q4 * 8;
            #pragma unroll
            for (int kk = 0; kk < 4; kk++) {
                float4 a0 = make_float4(0.f, 0.f, 0.f, 0.f), a1 = a0;
                if (vr) {
                    a0 = *(const float4*)(xp + kk * 32);
                    a1 = *(const float4*)(xp + kk * 32 + 4);
                }
                unsigned int u[4];
                u[0] = pk2(a0.x, a0.y); u[1] = pk2(a0.z, a0.w);
                u[2] = pk2(a1.x, a1.y); u[3] = pk2(a1.z, a1.w);
                afr[kk][rt] = *(short8*)u;
            }
        }
    }

    f32x4 acc[2][NT] = {};
    #pragma unroll
    for (int kk = 0; kk < 4; kk++) {
        #pragma unroll
        for (int ct = 0; ct < NT; ct++) {
            int n = ct * 16 + l16;
            short8 bf = *(const short8*)&sWT[n * WS + kk * 32 + q4 * 8];
            #pragma unroll
            for (int rt = 0; rt < 2; rt++)
                acc[rt][ct] = __builtin_amdgcn_mfma_f32_16x16x32_bf16(afr[kk][rt], bf, acc[rt][ct], 0, 0, 0);
        }
    }

    #pragma unroll
    for (int rt = 0; rt < 2; rt++) {
        #pragma unroll
        for (int q = 0; q < 4; q++) {
            int row = m0 + rt * 16 + q4 * 4 + q;
            if (row >= nRows) continue;
            #pragma unroll
            for (int ct = 0; ct < NT; ct++) {
                int colc = ct * 16 + l16;
                float v = acc[rt][ct][q];
                if (BIAS) v += bias[colc];
                if (ELU_ACT) v = v > 0.f ? v : (__expf(v) - 1.f);
                if (OUTM == 1) {
                    ((unsigned short*)Yv)[(size_t)row * KJ + colc] = f2bf(v);
                } else if (OUTM == 2) {
                    union { _Float16 hf; unsigned short us; } cv;
                    cv.hf = (_Float16)v;
                    ((unsigned short*)Yv)[(size_t)row * KJ + colc] = cv.us;
                } else {
                    ((float*)Yv)[(size_t)row * KJ + colc] = v;
                }
            }
        }
    }
}

// ---------------- layer-0 attention scores (reads bf16 h0), 4 nodes per wave ------------
// scores pre-scaled by log2e so downstream uses exp2 directly.

template <int H>
__global__ __launch_bounds__(256) void attn_scores16(const unsigned int* __restrict__ h2,
                                                     const float* __restrict__ a,
                                                     float* __restrict__ s_src,
                                                     float* __restrict__ s_dst, int n) {
    __shared__ float sa[H * 2 * 128];
    for (int i = threadIdx.x; i < H * 2 * 128; i += 256) sa[i] = a[i] * LOG2E;
    __syncthreads();
    int lane = threadIdx.x & 63, wv = threadIdx.x >> 6;
    int sub = lane & 15, g = lane >> 4;
    int node = (blockIdx.x * 4 + wv) * 4 + g;
    bool valid = node < n;
    int nd = valid ? node : 0;
    uint4 hv = *(const uint4*)&h2[(size_t)nd * 64 + sub * 4];
    float f[8];
    f[0] = bf2f(hv.x & 0xffffu); f[1] = bf2f(hv.x >> 16);
    f[2] = bf2f(hv.y & 0xffffu); f[3] = bf2f(hv.y >> 16);
    f[4] = bf2f(hv.z & 0xffffu); f[5] = bf2f(hv.z >> 16);
    f[6] = bf2f(hv.w & 0xffffu); f[7] = bf2f(hv.w >> 16);
    #pragma unroll
    for (int c = 0; c < 2 * H; c++) {
        const float* ap = &sa[c * 128 + sub * 8];
        float p = 0.f;
        #pragma unroll
        for (int q = 0; q < 8; q++) p += f[q] * ap[q];
        #pragma unroll
        for (int s = 1; s < 16; s <<= 1) p += __shfl_xor(p, s);
        if (sub == 0 && valid) {
            float* dst = (c & 1) ? s_dst : s_src;
            dst[node * H + (c >> 1)] = p;
        }
    }
}

// ---------------- edge pass: fp16 hW + v_dot2 aggregation + fused next-layer scores -----
// One wave per dst row; 16 lanes per row-slice, 4 edge-pair slots (g=lane>>4), each slot
// handles adjacent edges i+2g, i+2g+1 (single dwordx2 scol load). CSR rows padded to x8
// with dummy node (sdst=-1e30 -> w=0, hW row zeroed) so the loop has no validity logic.
// Depth-1 software pipeline: next iteration's scol/sdst/hW loads issue BEFORE current
// iteration's exp/dot2 compute (loop is latency-bound at ~2.5 iterations/row otherwise).

template <int DHT, int H, bool ELU_ACT, int HN, bool BF16O>
__global__ __launch_bounds__(256) void edge_agg_v(const unsigned int* __restrict__ hW2,
                                                  const float* __restrict__ ssrc,
                                                  const float* __restrict__ sdst,
                                                  const int* __restrict__ off,
                                                  const int* __restrict__ scol,
                                                  void* __restrict__ outv,
                                                  const float* __restrict__ a_next,
                                                  float* __restrict__ ssrc_n,
                                                  float* __restrict__ sdst_n, int nRows) {
    constexpr int FPL = DHT / 16;   // features per lane
    constexpr int UPL = FPL / 2;    // packed uints per lane
    constexpr int NC = (HN > 0) ? 2 * HN : 1;
    __shared__ float sAN[NC * 128];
    if (HN > 0) {
        for (int i = threadIdx.x; i < NC * 128; i += 256) sAN[i] = a_next[i] * LOG2E;
        __syncthreads();
    }
    int lane = threadIdx.x & 63;
    int sub = lane & 15;
    int g = lane >> 4;
    int wv = threadIdx.x >> 6;
    int r = __builtin_amdgcn_readfirstlane(blockIdx.x * 4 + wv);
    if (r >= nRows) return;
    int begin = off[r], end = off[r + 1];

    int head = (H == 4) ? (sub >> 2) : 0;
    float ssl = ssrc[r * H + head];

    float acc[FPL] = {};
    float den = 0.f;

    if (begin < end) {
        // prologue: load iteration 0
        int2 cc = *(const int2*)&scol[begin + 2 * g];
        float sdA = sdst[cc.x * H + head];
        float sdB = sdst[cc.y * H + head];
        unsigned int hA[UPL], hB[UPL];
        {
            int oA = cc.x * (DHT / 2) + sub * UPL;
            int oB = cc.y * (DHT / 2) + sub * UPL;
            if (UPL == 4) {
                *(uint4*)hA = *(const uint4*)&hW2[oA];
                *(uint4*)hB = *(const uint4*)&hW2[oB];
            } else {
                *(uint2*)hA = *(const uint2*)&hW2[oA];
                *(uint2*)hB = *(const uint2*)&hW2[oB];
            }
        }
        for (int i = begin + 8; i < end; i += 8) {
            // ---- prefetch next iteration (independent of current compute) ----
            int2 ccn = *(const int2*)&scol[i + 2 * g];
            float sdAn = sdst[ccn.x * H + head];
            float sdBn = sdst[ccn.y * H + head];
            unsigned int hAn[UPL], hBn[UPL];
            {
                int oA = ccn.x * (DHT / 2) + sub * UPL;
                int oB = ccn.y * (DHT / 2) + sub * UPL;
                if (UPL == 4) {
                    *(uint4*)hAn = *(const uint4*)&hW2[oA];
                    *(uint4*)hBn = *(const uint4*)&hW2[oB];
                } else {
                    *(uint2*)hAn = *(const uint2*)&hW2[oA];
                    *(uint2*)hBn = *(const uint2*)&hW2[oB];
                }
            }
            // ---- compute current ----
            float lgA = ssl + sdA;
            float wA = fexp2(fmaxf(lgA, LRELU_ALPHA * lgA));
            float lgB = ssl + sdB;
            float wB = fexp2(fmaxf(lgB, LRELU_ALPHA * lgB));
            den += wA + wB;
            h2v w2 = pkrtz(wA, wB);
            #pragma unroll
            for (int q = 0; q < UPL; q++) {
                acc[2 * q]     = dot2f(pack_lo(hA[q], hB[q]), w2, acc[2 * q]);
                acc[2 * q + 1] = dot2f(pack_hi(hA[q], hB[q]), w2, acc[2 * q + 1]);
            }
            // ---- rotate ----
            sdA = sdAn; sdB = sdBn;
            #pragma unroll
            for (int q = 0; q < UPL; q++) { hA[q] = hAn[q]; hB[q] = hBn[q]; }
        }
        // epilogue: compute last iteration
        float lgA = ssl + sdA;
        float wA = fexp2(fmaxf(lgA, LRELU_ALPHA * lgA));
        float lgB = ssl + sdB;
        float wB = fexp2(fmaxf(lgB, LRELU_ALPHA * lgB));
        den += wA + wB;
        h2v w2 = pkrtz(wA, wB);
        #pragma unroll
        for (int q = 0; q < UPL; q++) {
            acc[2 * q]     = dot2f(pack_lo(hA[q], hB[q]), w2, acc[2 * q]);
            acc[2 * q + 1] = dot2f(pack_hi(hA[q], hB[q]), w2, acc[2 * q + 1]);
        }
    }

    #pragma unroll
    for (int s = 16; s < 64; s <<= 1) {
        den += __shfl_xor(den, s);
        #pragma unroll
        for (int p = 0; p < FPL; p++) acc[p] += __shfl_xor(acc[p], s);
    }
    float inv = den > 0.f ? 1.f / den : 0.f;

    float v[FPL];
    #pragma unroll
    for (int p = 0; p < FPL; p++) {
        float tv = acc[p] * inv;
        if (ELU_ACT) tv = tv > 0.f ? tv : (__expf(tv) - 1.f);
        v[p] = tv;
    }

    if (DHT == 128) {
        if (BF16O)
            ((unsigned int*)outv)[(size_t)r * 64 + sub * 4 + g] = pk2(v[2 * g], v[2 * g + 1]);
        else
            *(float2*)&((float*)outv)[(size_t)r * 128 + sub * 8 + 2 * g] =
                make_float2(v[2 * g], v[2 * g + 1]);
    } else {
        ((float*)outv)[(size_t)r * DHT + sub * FPL + g] = v[g];
    }

    if (HN > 0) {
        constexpr int CPG = (HN == 4) ? 2 : 1;
        #pragma unroll
        for (int cc = 0; cc < CPG; cc++) {
            int c = (HN == 4) ? (g * 2 + cc) : (g & 1);
            const float* ap = &sAN[c * 128 + sub * FPL];
            float partial = 0.f;
            #pragma unroll
            for (int p = 0; p < FPL; p++) partial += v[p] * ap[p];
            #pragma unroll
            for (int s = 1; s < 16; s <<= 1) partial += __shfl_xor(partial, s);
            if (sub == 0 && (HN == 4 || g < 2)) {
                int hd = c >> 1;
                float* dst = (c & 1) ? sdst_n : ssrc_n;
                dst[r * HN + hd] = partial;
            }
        }
    }
}

// ---------------- launcher ----------------

extern "C" void kernel_launch(void* const* d_in, const int* in_sizes, int n_in,
                              void* d_out, int out_size, void* d_ws, size_t ws_size,
                              hipStream_t stream) {
    const float* x    = (const float*)d_in[0];
    const int*   ei   = (const int*)d_in[1];
    const float* Win  = (const float*)d_in[2];
    const float* bin  = (const float*)d_in[3];
    const float* ahid = (const float*)d_in[4];
    const float* Whid = (const float*)d_in[5];
    const float* aout = (const float*)d_in[6];
    const float* Wout = (const float*)d_in[7];
    float* out = (float*)d_out;

    const int N_ = in_sizes[0] / 128;
    const int E_ = in_sizes[1] / 2;

    char* p = (char*)d_ws;
    auto alloc = [&](size_t bytes) {
        char* q = p;
        p += (bytes + 511) & ~(size_t)511;
        return q;
    };
    int* counts = (int*)alloc((size_t)N_ * 4);
    int* tmp    = (int*)alloc((size_t)N_ * 4);
    int* rank   = (int*)alloc((size_t)E_ * 4);
    int* off    = (int*)alloc((size_t)(N_ + 1) * 4);
    int* bsum   = (int*)alloc(4096);
    int* scol   = (int*)alloc((size_t)(E_ + 8 * N_ + 64) * 4);   // padded CSR
    float* ssrcA = (float*)alloc((size_t)(N_ + 1) * 4 * 4);
    float* sdstA = (float*)alloc((size_t)(N_ + 1) * 4 * 4);
    float* ssrcB = (float*)alloc((size_t)(N_ + 1) * 4 * 4);
    float* sdstB = (float*)alloc((size_t)(N_ + 1) * 4 * 4);
    float* ssrcC = (float*)alloc((size_t)(N_ + 1) * 4);
    float* sdstC = (float*)alloc((size_t)(N_ + 1) * 4);
    unsigned int* hb  = (unsigned int*)alloc((size_t)N_ * 64 * 4);        // h  bf16 packed
    unsigned int* hWb = (unsigned int*)alloc((size_t)(N_ + 1) * 64 * 4);  // hW fp16 packed (+dummy row)
    unsigned short* WT0 = (unsigned short*)alloc(128 * 128 * 2);
    unsigned short* WT1 = (unsigned short*)alloc(128 * 128 * 2);
    unsigned short* WT2 = (unsigned short*)alloc(128 * 128 * 2);
    unsigned short* WT3 = (unsigned short*)alloc(64 * 128 * 2);

    int NB = (N_ + 255) / 256;
    int EB = (E_ + 255) / 256;
    int RT = (N_ + 127) / 128;
    int NW = (N_ + 3) / 4;
    int PADTOT = E_ + 8 * N_;

    // CSR by destination (= edge_index[0], the softmax segment key), rows padded to x8
    (void)hipMemsetAsync(counts, 0, (size_t)N_ * 4, stream);
    hist_k<<<EB, 256, 0, stream>>>(ei, counts, rank, E_);
    fill_pad_k<<<(PADTOT + 255) / 256, 256, 0, stream>>>(scol, sdstA, sdstB, sdstC, hWb, N_, PADTOT);
    scan_block_k<<<NB, 256, 0, stream>>>(counts, tmp, bsum, N_);
    scan_sums_k<<<1, 512, 0, stream>>>(bsum, NB);
    finalize_k<<<NB, 256, 0, stream>>>(tmp, bsum, off, N_);
    scatter_k<<<EB, 256, 0, stream>>>(ei, rank, off, scol, E_);

    // all weight repacks in one launch
    repack_all<<<224, 256, 0, stream>>>(Win, Whid, Wout, WT0, WT1, WT2, WT3);

    // input linear + ELU -> h0 bf16
    gemm_mfma<128, true, true, 1, false><<<RT, 256, 0, stream>>>(x, WT0, bin, hb, N_);

    // layer-0 attention scores (reads bf16 h0), log2e-scaled
    attn_scores16<4><<<(N_ + 15) / 16, 256, 0, stream>>>(hb, ahid, ssrcA, sdstA, N_);

    // hidden layer 1: hW0 = h0 @ Wcat0 (fp16) ; aggregate -> h1 bf16 (+ scores for a_hid[1])
    gemm_mfma<128, false, false, 2, true><<<RT, 256, 0, stream>>>(hb, WT1, nullptr, hWb, N_);
    edge_agg_v<128, 4, true, 4, true><<<NW, 256, 0, stream>>>(
        hWb, ssrcA, sdstA, off, scol, hb, ahid + 4 * 2 * 128, ssrcB, sdstB, N_);

    // hidden layer 2: hW1 = h1 @ Wcat1 (fp16) ; aggregate -> h2 bf16 (+ scores for a_out)
    gemm_mfma<128, false, false, 2, true><<<RT, 256, 0, stream>>>(hb, WT2, nullptr, hWb, N_);
    edge_agg_v<128, 4, true, 1, true><<<NW, 256, 0, stream>>>(
        hWb, ssrcB, sdstB, off, scol, hb, aout, ssrcC, sdstC, N_);

    // output layer: hW2 = h2 @ Wout (fp16) ; aggregate -> out fp32
    gemm_mfma<64, false, false, 2, true><<<RT, 256, 0, stream>>>(hb, WT3, nullptr, hWb, N_);
    edge_agg_v<64, 1, false, 0, false><<<NW, 256, 0, stream>>>(
        hWb, ssrcC, sdstC, off, scol, out, nullptr, nullptr, nullptr, N_);
}